// Round 7
// baseline (326.112 us; speedup 1.0000x reference)
//
#include <hip/hip_runtime.h>

#define HW 65536

typedef __attribute__((ext_vector_type(8))) short short8;
typedef __attribute__((ext_vector_type(4))) float float4v;

__device__ __forceinline__ int refl(int i){ if (i < 0) i = -i; if (i > 255) i = 510 - i; return i; }
__device__ __forceinline__ float lrelu(float x){ return x > 0.f ? x : 0.01f * x; }
__device__ __forceinline__ unsigned short f2bf(float x){
  union { float f; unsigned int u; } v; v.f = x;
  unsigned int r = v.u + 0x7fff + ((v.u >> 16) & 1);
  return (unsigned short)(r >> 16);
}

// ---------------- K1: bilinear grid sample (border, align_corners=False) ----------------
__global__ __launch_bounds__(256) void k_gridsample(const float* __restrict__ img,
                                                    const float* __restrict__ zern,
                                                    float* __restrict__ tilt){
  int x = threadIdx.x, y = blockIdx.x;
  int pix = y * 256 + x;
  float px = zern[pix * 35 + 0], py = zern[pix * 35 + 1];
  float ix = ((float)x + px) * (256.f / 255.f) - 0.5f;
  float iy = ((float)y + py) * (256.f / 255.f) - 0.5f;
  ix = fminf(fmaxf(ix, 0.f), 255.f);
  iy = fminf(fmaxf(iy, 0.f), 255.f);
  float x0f = floorf(ix), y0f = floorf(iy);
  float wx = ix - x0f, wy = iy - y0f;
  int x0 = (int)x0f, y0 = (int)y0f;
  int x1 = min(x0 + 1, 255), y1 = min(y0 + 1, 255);
  #pragma unroll
  for (int c = 0; c < 3; ++c){
    const float* im = img + c * HW;
    float g00 = im[y0 * 256 + x0], g01 = im[y0 * 256 + x1];
    float g10 = im[y1 * 256 + x0], g11 = im[y1 * 256 + x1];
    float top = g00 * (1.f - wx) + g01 * wx;
    float bot = g10 * (1.f - wx) + g11 * wx;
    tilt[c * HW + pix] = top * (1.f - wy) + bot * wy;
  }
}

// ---------------- Weight convert: fp32 -> zero-padded bf16 ------------------------------
#define W2OFF 13312
#define W3OFF 59904
__global__ __launch_bounds__(256) void k_wcvt(const float* __restrict__ w1,
    const float* __restrict__ w2, const float* __restrict__ w3,
    unsigned short* __restrict__ wbf){
  int i = blockIdx.x * 256 + threadIdx.x;
  if (i < 208 * 64){
    int n = i >> 6, k = i & 63;
    float v = (n < 200 && k < 33) ? w1[n * 33 + k] : 0.f;
    wbf[i] = f2bf(v);
  } else if (i < W2OFF + 208 * 224){
    int j = i - W2OFF; int n = j / 224, k = j - n * 224;
    float v = (n < 200 && k < 200) ? w2[n * 200 + k] : 0.f;
    wbf[i] = f2bf(v);
  } else if (i < 84992){
    int j = i - W3OFF; int n = j / 224, k = j - n * 224;
    float v = (n < 100 && k < 200) ? w3[n * 200 + k] : 0.f;
    wbf[i] = f2bf(v);
  }
}

// ---------------- Fused MLP: 64-pixel tile, 3 layers, MFMA bf16 -------------------------
#define HSTR 232
__global__ __launch_bounds__(256, 1) void k_mlp(const float* __restrict__ zern,
    const float* __restrict__ b1f, const float* __restrict__ b2f,
    const float* __restrict__ b3f, const unsigned short* __restrict__ wbf,
    float* __restrict__ coefp){
  __shared__ char smem[59392];
  unsigned short* H1 = (unsigned short*)smem;
  float*          H3 = (float*)smem;
  unsigned short* XB = (unsigned short*)(smem + 29696);
  unsigned short* H2 = XB;
  int tid = threadIdx.x;
  int pix0 = blockIdx.x * 64;
  int lane = tid & 63, wv = tid >> 6;
  int ln = lane & 15, qd = lane >> 4;

  for (int e = tid; e < 2304; e += 256) ((int*)XB)[e] = 0;
  for (int e = tid; e < 768; e += 256){
    int m = e / 12, j = e - m * 12;
    ((int*)H1)[m * 116 + 104 + j] = 0;
  }
  __syncthreads();
  for (int e = tid; e < 64 * 33; e += 256){
    int m = e / 33, k = e - m * 33;
    XB[m * 72 + k] = f2bf(zern[(pix0 + m) * 35 + 2 + k]);
  }
  __syncthreads();

  // ---- layer 1 ----
  for (int nt = wv; nt < 13; nt += 4){
    int n = nt * 16 + ln;
    short8 b0 = *(const short8*)(wbf + n * 64 + qd * 8);
    short8 b1 = *(const short8*)(wbf + n * 64 + 32 + qd * 8);
    float bv = (n < 200) ? b1f[n] : 0.f;
    #pragma unroll
    for (int mt = 0; mt < 4; ++mt){
      float4v acc = {bv, bv, bv, bv};
      short8 a0 = *(const short8*)(XB + (mt * 16 + ln) * 72 + qd * 8);
      short8 a1 = *(const short8*)(XB + (mt * 16 + ln) * 72 + 32 + qd * 8);
      acc = __builtin_amdgcn_mfma_f32_16x16x32_bf16(a0, b0, acc, 0, 0, 0);
      acc = __builtin_amdgcn_mfma_f32_16x16x32_bf16(a1, b1, acc, 0, 0, 0);
      #pragma unroll
      for (int r = 0; r < 4; ++r)
        H1[(mt * 16 + qd * 4 + r) * HSTR + n] = f2bf(lrelu(acc[r]));
    }
  }
  __syncthreads();

  // ---- layer 2 ----
  for (int e = tid; e < 768; e += 256){
    int m = e / 12, j = e - m * 12;
    ((int*)H2)[m * 116 + 104 + j] = 0;
  }
  {
    const unsigned short* w2p = wbf + W2OFF;
    for (int nt = wv; nt < 13; nt += 4){
      int n = nt * 16 + ln;
      short8 bf[7];
      #pragma unroll
      for (int kc = 0; kc < 7; ++kc)
        bf[kc] = *(const short8*)(w2p + n * 224 + kc * 32 + qd * 8);
      float bv = (n < 200) ? b2f[n] : 0.f;
      #pragma unroll
      for (int mt = 0; mt < 4; ++mt){
        float4v acc = {bv, bv, bv, bv};
        #pragma unroll
        for (int kc = 0; kc < 7; ++kc){
          short8 af = *(const short8*)(H1 + (mt * 16 + ln) * HSTR + kc * 32 + qd * 8);
          acc = __builtin_amdgcn_mfma_f32_16x16x32_bf16(af, bf[kc], acc, 0, 0, 0);
        }
        #pragma unroll
        for (int r = 0; r < 4; ++r)
          H2[(mt * 16 + qd * 4 + r) * HSTR + n] = f2bf(lrelu(acc[r]));
      }
    }
  }
  __syncthreads();

  // ---- layer 3 ----
  {
    const unsigned short* w3p = wbf + W3OFF;
    for (int nt = wv; nt < 7; nt += 4){
      int n = nt * 16 + ln;
      short8 bf[7];
      #pragma unroll
      for (int kc = 0; kc < 7; ++kc)
        bf[kc] = *(const short8*)(w3p + n * 224 + kc * 32 + qd * 8);
      float bv = (n < 100) ? b3f[n] : 0.f;
      #pragma unroll
      for (int mt = 0; mt < 4; ++mt){
        float4v acc = {bv, bv, bv, bv};
        #pragma unroll
        for (int kc = 0; kc < 7; ++kc){
          short8 af = *(const short8*)(H2 + (mt * 16 + ln) * HSTR + kc * 32 + qd * 8);
          acc = __builtin_amdgcn_mfma_f32_16x16x32_bf16(af, bf[kc], acc, 0, 0, 0);
        }
        #pragma unroll
        for (int r = 0; r < 4; ++r)
          H3[(mt * 16 + qd * 4 + r) * 113 + n] = acc[r];
      }
    }
  }
  __syncthreads();

  for (int e = tid; e < 100 * 64; e += 256){
    int n = e >> 6, m = e & 63;
    coefp[n * HW + pix0 + m] = H3[m * 113 + n];
  }
}

// ---------------- vertical conv pass: rolling 20-float register ring --------------------
__device__ __forceinline__ void vpass(const float* __restrict__ col,
                                      const float* __restrict__ kv, float acc[16]){
  float w[20];
  #pragma unroll
  for (int k = 0; k < 5; ++k){
    float4 v = *(const float4*)(col + 4 * k);
    w[4 * k] = v.x; w[4 * k + 1] = v.y; w[4 * k + 2] = v.z; w[4 * k + 3] = v.w;
  }
  #pragma unroll
  for (int u = 0; u < 64; u += 4){
    float k0 = kv[u * 10], k1 = kv[(u + 1) * 10], k2 = kv[(u + 2) * 10], k3 = kv[(u + 3) * 10];
    #pragma unroll
    for (int r = 0; r < 16; ++r)
      acc[r] += k0 * w[(u + r) % 20] + k1 * w[(u + r + 1) % 20]
              + k2 * w[(u + r + 2) % 20] + k3 * w[(u + r + 3) % 20];
    if (u < 60){
      float4 v = *(const float4*)(col + u + 20);
      int b = u % 20;
      w[b] = v.x; w[b + 1] = v.y; w[b + 2] = v.z; w[b + 3] = v.w;
    }
  }
  float k64 = kv[640];
  #pragma unroll
  for (int r = 0; r < 16; ++r) acc[r] += k64 * w[(64 + r) % 20];
}

// ---------------- K3 v5: full-height strips, all-i per block, register prefetch ---------
// bid < 640: (c 0..3, j 0..9, s 0..15): S_{c,j} = sum_i vconv(X_{c,i10+j}, L_i) -> sbuf
// bid >= 640: (c 0..2, s): Smu_{c,m} = vconv(tilt_c, mu_m), m = 0..9 -> smu
#define VSTR 324
__global__ __launch_bounds__(256, 4) void k_vconv5(const float* __restrict__ tilt,
    const float* __restrict__ coefp, const float* __restrict__ bl,
    const float* __restrict__ mu, float* __restrict__ sbuf,
    float* __restrict__ smu){
  __shared__ __align__(16) float sx[16 * VSTR];
  int tid = threadIdx.x;
  int bid = blockIdx.x;
  int tx = tid & 15, yg = tid >> 4;
  int yb = yg * 16;
  int t0 = tid >> 2, xq = tid & 3;

  int offs[5];
  #pragma unroll
  for (int k = 0; k < 5; ++k)
    offs[k] = refl(t0 + k * 64 - 32) * 256 + xq * 4;

  if (bid < 640){
    int s = bid & 15;
    int cj = bid >> 4;
    int c = cj / 10, j = cj - c * 10;
    int x0 = s * 16;
    float4 treg[5];
    if (c < 3){
      const float* tc = tilt + c * HW + x0;
      #pragma unroll
      for (int k = 0; k < 5; ++k) treg[k] = *(const float4*)(tc + offs[k]);
    }
    float4 pf[5];
    {
      const float* cq = coefp + j * HW + x0;
      #pragma unroll
      for (int k = 0; k < 5; ++k) pf[k] = *(const float4*)(cq + offs[k]);
    }
    float acc[16];
    #pragma unroll
    for (int r = 0; r < 16; ++r) acc[r] = 0.f;
    for (int i = 0; i < 10; ++i){
      __syncthreads();
      #pragma unroll
      for (int k = 0; k < 5; ++k){
        float4 v = pf[k];
        if (c < 3){ v.x *= treg[k].x; v.y *= treg[k].y; v.z *= treg[k].z; v.w *= treg[k].w; }
        int base = (xq * 4) * VSTR + t0 + k * 64;
        sx[base] = v.x; sx[base + VSTR] = v.y; sx[base + 2 * VSTR] = v.z; sx[base + 3 * VSTR] = v.w;
      }
      __syncthreads();
      if (i < 9){
        const float* cn = coefp + ((i + 1) * 10 + j) * HW + x0;
        #pragma unroll
        for (int k = 0; k < 5; ++k) pf[k] = *(const float4*)(cn + offs[k]);
      }
      vpass(sx + tx * VSTR + yb, bl + i, acc);
    }
    float* S = sbuf + (c * 10 + j) * HW;
    #pragma unroll
    for (int r = 0; r < 16; ++r)
      S[(yb + r) * 256 + x0 + tx] = acc[r];
  } else {
    int b2 = bid - 640;
    int c = b2 >> 4;
    int s = b2 & 15;
    int x0 = s * 16;
    const float* tc = tilt + c * HW + x0;
    #pragma unroll
    for (int k = 0; k < 5; ++k){
      float4 v = *(const float4*)(tc + offs[k]);
      int base = (xq * 4) * VSTR + t0 + k * 64;
      sx[base] = v.x; sx[base + VSTR] = v.y; sx[base + 2 * VSTR] = v.z; sx[base + 3 * VSTR] = v.w;
    }
    __syncthreads();
    const float* col = sx + tx * VSTR + yb;
    for (int m = 0; m < 10; ++m){
      float acc[16];
      #pragma unroll
      for (int r = 0; r < 16; ++r) acc[r] = 0.f;
      vpass(col, mu + m, acc);
      float* S = smu + (c * 10 + m) * HW;
      #pragma unroll
      for (int r = 0; r < 16; ++r)
        S[(yb + r) * 256 + x0 + tx] = acc[r];
    }
  }
}

// ---------------- K4 v5: horizontal conv, 14 groups x 64 y-tiles ------------------------
// grp 0..7:  (tgt 0..3, half h): sum_{j in [5h,5h+5)} hconv(S_{tgt,j}, R_j)   -> part[grp]
// grp 8..13: (tgt 0..2, half h): sum_{m in [5h,5h+5)} hconv(Smu_{tgt,m}, mu_m) -> part[grp]
__global__ __launch_bounds__(256) void k_hconv5(const float* __restrict__ sbuf,
    const float* __restrict__ smu, const float* __restrict__ br,
    const float* __restrict__ mu, float* __restrict__ part){
  __shared__ __align__(16) float sr[4][320];
  int tid = threadIdx.x;
  int grp = blockIdx.x >> 6;
  int yt = blockIdx.x & 63;
  int r = tid >> 6, xg = tid & 63, x0 = xg * 4;
  int isbr = (grp < 8);
  int tgt, h;
  if (isbr){ tgt = grp >> 1; h = grp & 1; }
  else     { int g2 = grp - 8; tgt = g2 >> 1; h = g2 & 1; }
  const float* kp   = isbr ? br : mu;
  const float* base = isbr ? (sbuf + tgt * 10 * HW) : (smu + tgt * 10 * HW);
  float a0 = 0.f, a1 = 0.f, a2 = 0.f, a3 = 0.f;
  for (int p = 0; p < 5; ++p){
    int col = h * 5 + p;
    const float* plane = base + col * HW;
    __syncthreads();
    for (int e = tid; e < 1280; e += 256){
      int rr = e / 320, ii = e - rr * 320;
      sr[rr][ii] = plane[(yt * 4 + rr) * 256 + refl(ii - 32)];
    }
    __syncthreads();
    float4 av = *(const float4*)&sr[r][x0];
    for (int u = 0; u < 64; u += 4){
      float4 bv = *(const float4*)&sr[r][x0 + u + 4];
      float k0 = kp[u * 10 + col],       k1 = kp[(u + 1) * 10 + col],
            k2 = kp[(u + 2) * 10 + col], k3 = kp[(u + 3) * 10 + col];
      a0 += k0 * av.x + k1 * av.y + k2 * av.z + k3 * av.w;
      a1 += k0 * av.y + k1 * av.z + k2 * av.w + k3 * bv.x;
      a2 += k0 * av.z + k1 * av.w + k2 * bv.x + k3 * bv.y;
      a3 += k0 * av.w + k1 * bv.x + k2 * bv.y + k3 * bv.z;
      av = bv;
    }
    float k64 = kp[640 + col];
    a0 += k64 * av.x; a1 += k64 * av.y; a2 += k64 * av.z; a3 += k64 * av.w;
  }
  float4 res = {a0, a1, a2, a3};
  *(float4*)(part + grp * HW + (yt * 4 + r) * 256 + x0) = res;
}

// ---------------- K5: out_c = (P2c+P2c+1+P8+2c+P9+2c) / (P6+P7+muC) ---------------------
__global__ __launch_bounds__(256) void k_final(const float* __restrict__ part,
                                               const float* __restrict__ mu,
                                               float* __restrict__ out){
  int pix = blockIdx.x * 256 + threadIdx.x;
  float muC = 0.f;
  #pragma unroll
  for (int m = 0; m < 10; ++m){
    float s = 0.f;
    for (int u = 0; u < 65; ++u) s += mu[u * 10 + m];
    muC += s * s;
  }
  float den = part[6 * HW + pix] + part[7 * HW + pix] + muC;
  float inv = 1.f / den;
  #pragma unroll
  for (int c = 0; c < 3; ++c){
    float num = part[(2 * c) * HW + pix] + part[(2 * c + 1) * HW + pix]
              + part[(8 + 2 * c) * HW + pix] + part[(9 + 2 * c) * HW + pix];
    out[c * HW + pix] = num * inv;
  }
}

extern "C" void kernel_launch(void* const* d_in, const int* in_sizes, int n_in,
                              void* d_out, int out_size, void* d_ws, size_t ws_size,
                              hipStream_t stream) {
  const float* img  = (const float*)d_in[0];
  const float* zern = (const float*)d_in[1];
  const float* w1   = (const float*)d_in[2];
  const float* b1   = (const float*)d_in[3];
  const float* w2   = (const float*)d_in[4];
  const float* b2   = (const float*)d_in[5];
  const float* w3   = (const float*)d_in[6];
  const float* b3   = (const float*)d_in[7];
  const float* bl   = (const float*)d_in[8];
  const float* br   = (const float*)d_in[9];
  const float* mu   = (const float*)d_in[10];
  float* out = (float*)d_out;

  float* w     = (float*)d_ws;
  float* tilt  = w;              // planes [0,3)
  float* coefp = w + 3 * HW;     // planes [3,103); dead after vconv5
  float* part  = w + 3 * HW;     // planes [3,17): hconv partials (reuse coefp region)
  float* sbuf  = w + 103 * HW;   // planes [103,143)
  float* smu   = w + 143 * HW;   // planes [143,173)
  unsigned short* wbf = (unsigned short*)sbuf; // bf16 weights, dead before vconv5 writes

  k_gridsample<<<256, 256, 0, stream>>>(img, zern, tilt);
  k_wcvt<<<332, 256, 0, stream>>>(w1, w2, w3, wbf);
  k_mlp<<<1024, 256, 0, stream>>>(zern, b1, b2, b3, wbf, coefp);
  k_vconv5<<<688, 256, 0, stream>>>(tilt, coefp, bl, mu, sbuf, smu);
  k_hconv5<<<896, 256, 0, stream>>>(sbuf, smu, br, mu, part);
  k_final<<<256, 256, 0, stream>>>(part, mu, out);
}

// Round 8
// 226.429 us; speedup vs baseline: 1.4402x; 1.4402x over previous
//
#include <hip/hip_runtime.h>

#define HW 65536

typedef __attribute__((ext_vector_type(8))) short short8;
typedef __attribute__((ext_vector_type(4))) float float4v;

__device__ __forceinline__ int refl(int i){ if (i < 0) i = -i; if (i > 255) i = 510 - i; return i; }
__device__ __forceinline__ float lrelu(float x){ return x > 0.f ? x : 0.01f * x; }
__device__ __forceinline__ unsigned short f2bf(float x){
  union { float f; unsigned int u; } v; v.f = x;
  unsigned int r = v.u + 0x7fff + ((v.u >> 16) & 1);
  return (unsigned short)(r >> 16);
}

// ---------------- K1: bilinear grid sample (border, align_corners=False) ----------------
__global__ __launch_bounds__(256) void k_gridsample(const float* __restrict__ img,
                                                    const float* __restrict__ zern,
                                                    float* __restrict__ tilt){
  int x = threadIdx.x, y = blockIdx.x;
  int pix = y * 256 + x;
  float px = zern[pix * 35 + 0], py = zern[pix * 35 + 1];
  float ix = ((float)x + px) * (256.f / 255.f) - 0.5f;
  float iy = ((float)y + py) * (256.f / 255.f) - 0.5f;
  ix = fminf(fmaxf(ix, 0.f), 255.f);
  iy = fminf(fmaxf(iy, 0.f), 255.f);
  float x0f = floorf(ix), y0f = floorf(iy);
  float wx = ix - x0f, wy = iy - y0f;
  int x0 = (int)x0f, y0 = (int)y0f;
  int x1 = min(x0 + 1, 255), y1 = min(y0 + 1, 255);
  #pragma unroll
  for (int c = 0; c < 3; ++c){
    const float* im = img + c * HW;
    float g00 = im[y0 * 256 + x0], g01 = im[y0 * 256 + x1];
    float g10 = im[y1 * 256 + x0], g11 = im[y1 * 256 + x1];
    float top = g00 * (1.f - wx) + g01 * wx;
    float bot = g10 * (1.f - wx) + g11 * wx;
    tilt[c * HW + pix] = top * (1.f - wy) + bot * wy;
  }
}

// ---------------- Weight convert: fp32 -> zero-padded bf16 ------------------------------
#define W2OFF 13312
#define W3OFF 59904
__global__ __launch_bounds__(256) void k_wcvt(const float* __restrict__ w1,
    const float* __restrict__ w2, const float* __restrict__ w3,
    unsigned short* __restrict__ wbf){
  int i = blockIdx.x * 256 + threadIdx.x;
  if (i < 208 * 64){
    int n = i >> 6, k = i & 63;
    float v = (n < 200 && k < 33) ? w1[n * 33 + k] : 0.f;
    wbf[i] = f2bf(v);
  } else if (i < W2OFF + 208 * 224){
    int j = i - W2OFF; int n = j / 224, k = j - n * 224;
    float v = (n < 200 && k < 200) ? w2[n * 200 + k] : 0.f;
    wbf[i] = f2bf(v);
  } else if (i < 84992){
    int j = i - W3OFF; int n = j / 224, k = j - n * 224;
    float v = (n < 100 && k < 200) ? w3[n * 200 + k] : 0.f;
    wbf[i] = f2bf(v);
  }
}

// ---------------- Fused MLP: 64-pixel tile, 3 layers, MFMA bf16 -------------------------
#define HSTR 232
__global__ __launch_bounds__(256, 1) void k_mlp(const float* __restrict__ zern,
    const float* __restrict__ b1f, const float* __restrict__ b2f,
    const float* __restrict__ b3f, const unsigned short* __restrict__ wbf,
    float* __restrict__ coefp){
  __shared__ char smem[59392];
  unsigned short* H1 = (unsigned short*)smem;
  float*          H3 = (float*)smem;
  unsigned short* XB = (unsigned short*)(smem + 29696);
  unsigned short* H2 = XB;
  int tid = threadIdx.x;
  int pix0 = blockIdx.x * 64;
  int lane = tid & 63, wv = tid >> 6;
  int ln = lane & 15, qd = lane >> 4;

  for (int e = tid; e < 2304; e += 256) ((int*)XB)[e] = 0;
  for (int e = tid; e < 768; e += 256){
    int m = e / 12, j = e - m * 12;
    ((int*)H1)[m * 116 + 104 + j] = 0;
  }
  __syncthreads();
  for (int e = tid; e < 64 * 33; e += 256){
    int m = e / 33, k = e - m * 33;
    XB[m * 72 + k] = f2bf(zern[(pix0 + m) * 35 + 2 + k]);
  }
  __syncthreads();

  // ---- layer 1 ----
  for (int nt = wv; nt < 13; nt += 4){
    int n = nt * 16 + ln;
    short8 b0 = *(const short8*)(wbf + n * 64 + qd * 8);
    short8 b1 = *(const short8*)(wbf + n * 64 + 32 + qd * 8);
    float bv = (n < 200) ? b1f[n] : 0.f;
    #pragma unroll
    for (int mt = 0; mt < 4; ++mt){
      float4v acc = {bv, bv, bv, bv};
      short8 a0 = *(const short8*)(XB + (mt * 16 + ln) * 72 + qd * 8);
      short8 a1 = *(const short8*)(XB + (mt * 16 + ln) * 72 + 32 + qd * 8);
      acc = __builtin_amdgcn_mfma_f32_16x16x32_bf16(a0, b0, acc, 0, 0, 0);
      acc = __builtin_amdgcn_mfma_f32_16x16x32_bf16(a1, b1, acc, 0, 0, 0);
      #pragma unroll
      for (int r = 0; r < 4; ++r)
        H1[(mt * 16 + qd * 4 + r) * HSTR + n] = f2bf(lrelu(acc[r]));
    }
  }
  __syncthreads();

  // ---- layer 2 ----
  for (int e = tid; e < 768; e += 256){
    int m = e / 12, j = e - m * 12;
    ((int*)H2)[m * 116 + 104 + j] = 0;
  }
  {
    const unsigned short* w2p = wbf + W2OFF;
    for (int nt = wv; nt < 13; nt += 4){
      int n = nt * 16 + ln;
      short8 bf[7];
      #pragma unroll
      for (int kc = 0; kc < 7; ++kc)
        bf[kc] = *(const short8*)(w2p + n * 224 + kc * 32 + qd * 8);
      float bv = (n < 200) ? b2f[n] : 0.f;
      #pragma unroll
      for (int mt = 0; mt < 4; ++mt){
        float4v acc = {bv, bv, bv, bv};
        #pragma unroll
        for (int kc = 0; kc < 7; ++kc){
          short8 af = *(const short8*)(H1 + (mt * 16 + ln) * HSTR + kc * 32 + qd * 8);
          acc = __builtin_amdgcn_mfma_f32_16x16x32_bf16(af, bf[kc], acc, 0, 0, 0);
        }
        #pragma unroll
        for (int r = 0; r < 4; ++r)
          H2[(mt * 16 + qd * 4 + r) * HSTR + n] = f2bf(lrelu(acc[r]));
      }
    }
  }
  __syncthreads();

  // ---- layer 3 ----
  {
    const unsigned short* w3p = wbf + W3OFF;
    for (int nt = wv; nt < 7; nt += 4){
      int n = nt * 16 + ln;
      short8 bf[7];
      #pragma unroll
      for (int kc = 0; kc < 7; ++kc)
        bf[kc] = *(const short8*)(w3p + n * 224 + kc * 32 + qd * 8);
      float bv = (n < 100) ? b3f[n] : 0.f;
      #pragma unroll
      for (int mt = 0; mt < 4; ++mt){
        float4v acc = {bv, bv, bv, bv};
        #pragma unroll
        for (int kc = 0; kc < 7; ++kc){
          short8 af = *(const short8*)(H2 + (mt * 16 + ln) * HSTR + kc * 32 + qd * 8);
          acc = __builtin_amdgcn_mfma_f32_16x16x32_bf16(af, bf[kc], acc, 0, 0, 0);
        }
        #pragma unroll
        for (int r = 0; r < 4; ++r)
          H3[(mt * 16 + qd * 4 + r) * 113 + n] = acc[r];
      }
    }
  }
  __syncthreads();

  for (int e = tid; e < 100 * 64; e += 256){
    int n = e >> 6, m = e & 63;
    coefp[n * HW + pix0 + m] = H3[m * 113 + n];
  }
}

// ---------------- vertical conv pass: rolling 20-float register ring --------------------
__device__ __forceinline__ void vpass(const float* __restrict__ col,
                                      const float* __restrict__ kv, float acc[16]){
  float w[20];
  #pragma unroll
  for (int k = 0; k < 5; ++k){
    float4 v = *(const float4*)(col + 4 * k);
    w[4 * k] = v.x; w[4 * k + 1] = v.y; w[4 * k + 2] = v.z; w[4 * k + 3] = v.w;
  }
  #pragma unroll
  for (int u = 0; u < 64; u += 4){
    float k0 = kv[u * 10], k1 = kv[(u + 1) * 10], k2 = kv[(u + 2) * 10], k3 = kv[(u + 3) * 10];
    #pragma unroll
    for (int r = 0; r < 16; ++r)
      acc[r] += k0 * w[(u + r) % 20] + k1 * w[(u + r + 1) % 20]
              + k2 * w[(u + r + 2) % 20] + k3 * w[(u + r + 3) % 20];
    if (u < 60){
      float4 v = *(const float4*)(col + u + 20);
      int b = u % 20;
      w[b] = v.x; w[b + 1] = v.y; w[b + 2] = v.z; w[b + 3] = v.w;
    }
  }
  float k64 = kv[640];
  #pragma unroll
  for (int r = 0; r < 16; ++r) acc[r] += k64 * w[(64 + r) % 20];
}

// ---------------- K3 v6: full-height strips, all-i per block, register prefetch ---------
// bid < 640: (c 0..3, j 0..9, s 0..15): S_{c,j} = sum_i vconv(X_{c,i10+j}, L_i) -> sbuf
// bid >= 640: (c 0..2, s): Smu_{c,m} = vconv(tilt_c, mu_m), m = 0..9 -> smu
// NOTE: natural VGPR allocation (no min-waves clamp) — (256,4) forced 64 VGPR and spilled
// 400 MB of scratch traffic (R7). Live set ~90 floats needs ~128+ VGPRs.
#define VSTR 324
__global__ __launch_bounds__(256) void k_vconv6(const float* __restrict__ tilt,
    const float* __restrict__ coefp, const float* __restrict__ bl,
    const float* __restrict__ mu, float* __restrict__ sbuf,
    float* __restrict__ smu){
  __shared__ __align__(16) float sx[16 * VSTR];
  int tid = threadIdx.x;
  int bid = blockIdx.x;
  int tx = tid & 15, yg = tid >> 4;
  int yb = yg * 16;
  int t0 = tid >> 2, xq = tid & 3;

  int offs[5];
  #pragma unroll
  for (int k = 0; k < 5; ++k)
    offs[k] = refl(t0 + k * 64 - 32) * 256 + xq * 4;

  if (bid < 640){
    int s = bid & 15;
    int cj = bid >> 4;
    int c = cj / 10, j = cj - c * 10;
    int x0 = s * 16;
    float4 treg[5];
    if (c < 3){
      const float* tc = tilt + c * HW + x0;
      #pragma unroll
      for (int k = 0; k < 5; ++k) treg[k] = *(const float4*)(tc + offs[k]);
    }
    float4 pf[5];
    {
      const float* cq = coefp + j * HW + x0;
      #pragma unroll
      for (int k = 0; k < 5; ++k) pf[k] = *(const float4*)(cq + offs[k]);
    }
    float acc[16];
    #pragma unroll
    for (int r = 0; r < 16; ++r) acc[r] = 0.f;
    for (int i = 0; i < 10; ++i){
      __syncthreads();
      #pragma unroll
      for (int k = 0; k < 5; ++k){
        float4 v = pf[k];
        if (c < 3){ v.x *= treg[k].x; v.y *= treg[k].y; v.z *= treg[k].z; v.w *= treg[k].w; }
        int base = (xq * 4) * VSTR + t0 + k * 64;
        sx[base] = v.x; sx[base + VSTR] = v.y; sx[base + 2 * VSTR] = v.z; sx[base + 3 * VSTR] = v.w;
      }
      __syncthreads();
      if (i < 9){
        const float* cn = coefp + ((i + 1) * 10 + j) * HW + x0;
        #pragma unroll
        for (int k = 0; k < 5; ++k) pf[k] = *(const float4*)(cn + offs[k]);
      }
      vpass(sx + tx * VSTR + yb, bl + i, acc);
    }
    float* S = sbuf + (c * 10 + j) * HW;
    #pragma unroll
    for (int r = 0; r < 16; ++r)
      S[(yb + r) * 256 + x0 + tx] = acc[r];
  } else {
    int b2 = bid - 640;
    int c = b2 >> 4;
    int s = b2 & 15;
    int x0 = s * 16;
    const float* tc = tilt + c * HW + x0;
    #pragma unroll
    for (int k = 0; k < 5; ++k){
      float4 v = *(const float4*)(tc + offs[k]);
      int base = (xq * 4) * VSTR + t0 + k * 64;
      sx[base] = v.x; sx[base + VSTR] = v.y; sx[base + 2 * VSTR] = v.z; sx[base + 3 * VSTR] = v.w;
    }
    __syncthreads();
    const float* col = sx + tx * VSTR + yb;
    for (int m = 0; m < 10; ++m){
      float acc[16];
      #pragma unroll
      for (int r = 0; r < 16; ++r) acc[r] = 0.f;
      vpass(col, mu + m, acc);
      float* S = smu + (c * 10 + m) * HW;
      #pragma unroll
      for (int r = 0; r < 16; ++r)
        S[(yb + r) * 256 + x0 + tx] = acc[r];
    }
  }
}

// ---------------- K4 v5: horizontal conv, 14 groups x 64 y-tiles ------------------------
// grp 0..7:  (tgt 0..3, half h): sum_{j in [5h,5h+5)} hconv(S_{tgt,j}, R_j)   -> part[grp]
// grp 8..13: (tgt 0..2, half h): sum_{m in [5h,5h+5)} hconv(Smu_{tgt,m}, mu_m) -> part[grp]
__global__ __launch_bounds__(256) void k_hconv5(const float* __restrict__ sbuf,
    const float* __restrict__ smu, const float* __restrict__ br,
    const float* __restrict__ mu, float* __restrict__ part){
  __shared__ __align__(16) float sr[4][320];
  int tid = threadIdx.x;
  int grp = blockIdx.x >> 6;
  int yt = blockIdx.x & 63;
  int r = tid >> 6, xg = tid & 63, x0 = xg * 4;
  int isbr = (grp < 8);
  int tgt, h;
  if (isbr){ tgt = grp >> 1; h = grp & 1; }
  else     { int g2 = grp - 8; tgt = g2 >> 1; h = g2 & 1; }
  const float* kp   = isbr ? br : mu;
  const float* base = isbr ? (sbuf + tgt * 10 * HW) : (smu + tgt * 10 * HW);
  float a0 = 0.f, a1 = 0.f, a2 = 0.f, a3 = 0.f;
  for (int p = 0; p < 5; ++p){
    int col = h * 5 + p;
    const float* plane = base + col * HW;
    __syncthreads();
    for (int e = tid; e < 1280; e += 256){
      int rr = e / 320, ii = e - rr * 320;
      sr[rr][ii] = plane[(yt * 4 + rr) * 256 + refl(ii - 32)];
    }
    __syncthreads();
    float4 av = *(const float4*)&sr[r][x0];
    for (int u = 0; u < 64; u += 4){
      float4 bv = *(const float4*)&sr[r][x0 + u + 4];
      float k0 = kp[u * 10 + col],       k1 = kp[(u + 1) * 10 + col],
            k2 = kp[(u + 2) * 10 + col], k3 = kp[(u + 3) * 10 + col];
      a0 += k0 * av.x + k1 * av.y + k2 * av.z + k3 * av.w;
      a1 += k0 * av.y + k1 * av.z + k2 * av.w + k3 * bv.x;
      a2 += k0 * av.z + k1 * av.w + k2 * bv.x + k3 * bv.y;
      a3 += k0 * av.w + k1 * bv.x + k2 * bv.y + k3 * bv.z;
      av = bv;
    }
    float k64 = kp[640 + col];
    a0 += k64 * av.x; a1 += k64 * av.y; a2 += k64 * av.z; a3 += k64 * av.w;
  }
  float4 res = {a0, a1, a2, a3};
  *(float4*)(part + grp * HW + (yt * 4 + r) * 256 + x0) = res;
}

// ---------------- K5: out_c = (P2c+P2c+1+P8+2c+P9+2c) / (P6+P7+muC) ---------------------
__global__ __launch_bounds__(256) void k_final(const float* __restrict__ part,
                                               const float* __restrict__ mu,
                                               float* __restrict__ out){
  int pix = blockIdx.x * 256 + threadIdx.x;
  float muC = 0.f;
  #pragma unroll
  for (int m = 0; m < 10; ++m){
    float s = 0.f;
    for (int u = 0; u < 65; ++u) s += mu[u * 10 + m];
    muC += s * s;
  }
  float den = part[6 * HW + pix] + part[7 * HW + pix] + muC;
  float inv = 1.f / den;
  #pragma unroll
  for (int c = 0; c < 3; ++c){
    float num = part[(2 * c) * HW + pix] + part[(2 * c + 1) * HW + pix]
              + part[(8 + 2 * c) * HW + pix] + part[(9 + 2 * c) * HW + pix];
    out[c * HW + pix] = num * inv;
  }
}

extern "C" void kernel_launch(void* const* d_in, const int* in_sizes, int n_in,
                              void* d_out, int out_size, void* d_ws, size_t ws_size,
                              hipStream_t stream) {
  const float* img  = (const float*)d_in[0];
  const float* zern = (const float*)d_in[1];
  const float* w1   = (const float*)d_in[2];
  const float* b1   = (const float*)d_in[3];
  const float* w2   = (const float*)d_in[4];
  const float* b2   = (const float*)d_in[5];
  const float* w3   = (const float*)d_in[6];
  const float* b3   = (const float*)d_in[7];
  const float* bl   = (const float*)d_in[8];
  const float* br   = (const float*)d_in[9];
  const float* mu   = (const float*)d_in[10];
  float* out = (float*)d_out;

  float* w     = (float*)d_ws;
  float* tilt  = w;              // planes [0,3)
  float* coefp = w + 3 * HW;     // planes [3,103); dead after vconv6
  float* part  = w + 3 * HW;     // planes [3,17): hconv partials (reuse coefp region)
  float* sbuf  = w + 103 * HW;   // planes [103,143)
  float* smu   = w + 143 * HW;   // planes [143,173)
  unsigned short* wbf = (unsigned short*)sbuf; // bf16 weights, dead before vconv6 writes

  k_gridsample<<<256, 256, 0, stream>>>(img, zern, tilt);
  k_wcvt<<<332, 256, 0, stream>>>(w1, w2, w3, wbf);
  k_mlp<<<1024, 256, 0, stream>>>(zern, b1, b2, b3, wbf, coefp);
  k_vconv6<<<688, 256, 0, stream>>>(tilt, coefp, bl, mu, sbuf, smu);
  k_hconv5<<<896, 256, 0, stream>>>(sbuf, smu, br, mu, part);
  k_final<<<256, 256, 0, stream>>>(part, mu, out);
}